// Round 11
// baseline (187.729 us; speedup 1.0000x reference)
//
#include <hip/hip_runtime.h>
#include <hip/hip_bf16.h>
#include <math.h>

#define LSQ_EPS 1e-8f
#define BUCKET_BITS 7
#define BUCKET_SIZE 128            // nodes per bucket (scatter granularity)
#define NB_MAX 800                 // max buckets supported by static LDS
#define CAP 8960                   // per-bucket payload capacity (mean ~8184, sigma ~90)
#define CAP_HALF 4608              // per-half-bucket capacity (mean ~4092, sigma ~64, 8 sigma)
#define SCAT_BLOCKS 1024           // R8-proven: 5 blocks/CU, WRITE ~50 MB
#define STAGE_CAP 6272             // >= 2 * chunk (chunk = ceil(E2/1024) -> 3128)

// ---------------------------------------------------------------------------
// Pass 1 (fused pack + sorted scatter) — byte-exact R8 configuration, the
// empirically write-optimal point (R6: 512blk/37MB/75us slow-occ; R8:
// 1024blk/50MB/56us; R9: 1536blk/88MB/76us; R10 reg-cache variant: 75MB/60us).
// eidx re-read in phase 3 is L3-hot and FREE — do not "optimize" it away.
// payload u32 = (node_local << 17) | other_node
// ---------------------------------------------------------------------------
__device__ __forceinline__ void hinc(unsigned int* hp, int b) {
    atomicAdd(&hp[b >> 1], 1u << ((b & 1) * 16));
}
__device__ __forceinline__ int hget(const unsigned int* hp, int b) {
    return (int)((hp[b >> 1] >> ((b & 1) * 16)) & 0xFFFFu);
}

__global__ __launch_bounds__(256, 5) void lsq_scatter_sorted(
    const float* __restrict__ pos, const float* __restrict__ phi,
    const int* __restrict__ eidx, int E, int N, int NB,
    float4* __restrict__ pp4,
    unsigned int* __restrict__ region, int* __restrict__ g_cursor)
{
    __shared__ unsigned int staged[STAGE_CAP];     // 25.1 KB
    __shared__ unsigned int histp[NB_MAX / 2];     // 1.6 KB (2x16-bit packed)
    __shared__ unsigned int cnt2p[NB_MAX / 2];     // 1.6 KB (2x16-bit packed)
    __shared__ unsigned short base16[NB_MAX];      // 1.6 KB
    __shared__ unsigned short sstart16[NB_MAX];    // 1.6 KB

    const int tid = threadIdx.x;
    const int E2 = E >> 1;

    // fused pack: pp4[i] = (pos, phi)
    for (int i = blockIdx.x * 256 + tid; i < N; i += SCAT_BLOCKS * 256)
        pp4[i] = make_float4(pos[3 * i + 0], pos[3 * i + 1], pos[3 * i + 2], phi[i]);

    int chunk = (E2 + SCAT_BLOCKS - 1) / SCAT_BLOCKS;
    chunk = (chunk + 3) & ~3;
    const int start = blockIdx.x * chunk;
    const int end = min(start + chunk, E2);
    if (start >= E2) return;

    for (int t = tid; t < NB_MAX / 2; t += 256) { histp[t] = 0; cnt2p[t] = 0; }
    __syncthreads();

    // phase 1: histogram BOTH endpoints
    const int nvec = (end - start) & ~3;
    for (int e = start + (tid << 2); e < start + nvec; e += 1024) {
        int4 r = *(const int4*)(eidx + e);
        int4 c = *(const int4*)(eidx + E + e);
        hinc(histp, r.x >> BUCKET_BITS);
        hinc(histp, r.y >> BUCKET_BITS);
        hinc(histp, r.z >> BUCKET_BITS);
        hinc(histp, r.w >> BUCKET_BITS);
        hinc(histp, c.x >> BUCKET_BITS);
        hinc(histp, c.y >> BUCKET_BITS);
        hinc(histp, c.z >> BUCKET_BITS);
        hinc(histp, c.w >> BUCKET_BITS);
    }
    for (int e = start + nvec + tid; e < end; e += 256) {
        hinc(histp, eidx[e] >> BUCKET_BITS);
        hinc(histp, eidx[E + e] >> BUCKET_BITS);
    }
    __syncthreads();

    // phase 2a: global reservation (one int atomic per non-empty bucket)
    for (int b = tid; b < NB; b += 256) {
        int c = hget(histp, b);
        int bs = (c > 0) ? atomicAdd(&g_cursor[b], c) : 0;
        base16[b] = (unsigned short)min(bs, 65535);
    }
    // phase 2b: block-local exclusive scan of hist -> sstart16 (wave 0)
    if (tid < 64) {
        int carry = 0;
        for (int bi = 0; bi < NB; bi += 64) {
            int b = bi + tid;
            int c = (b < NB) ? hget(histp, b) : 0;
            int x = c;
#pragma unroll
            for (int d = 1; d < 64; d <<= 1) {
                int y = __shfl_up(x, d, 64);
                if (tid >= d) x += y;
            }
            if (b < NB) sstart16[b] = (unsigned short)(carry + x - c);
            carry += __shfl(x, 63, 64);
        }
    }
    __syncthreads();

    // phase 3: counting-sort payloads into LDS staging (eidx re-read: L3-hot)
    for (int e = start + (tid << 2); e < start + nvec; e += 1024) {
        int4 r = *(const int4*)(eidx + e);
        int4 c = *(const int4*)(eidx + E + e);
        int rr[4] = {r.x, r.y, r.z, r.w};
        int cc[4] = {c.x, c.y, c.z, c.w};
#pragma unroll
        for (int k = 0; k < 4; ++k) {
            int b1 = rr[k] >> BUCKET_BITS;
            unsigned int o1 = atomicAdd(&cnt2p[b1 >> 1], 1u << ((b1 & 1) * 16));
            int s1 = (int)sstart16[b1] + (int)((o1 >> ((b1 & 1) * 16)) & 0xFFFFu);
            staged[s1] = ((unsigned int)(rr[k] & (BUCKET_SIZE - 1)) << 17) | (unsigned int)cc[k];
            int b2 = cc[k] >> BUCKET_BITS;
            unsigned int o2 = atomicAdd(&cnt2p[b2 >> 1], 1u << ((b2 & 1) * 16));
            int s2 = (int)sstart16[b2] + (int)((o2 >> ((b2 & 1) * 16)) & 0xFFFFu);
            staged[s2] = ((unsigned int)(cc[k] & (BUCKET_SIZE - 1)) << 17) | (unsigned int)rr[k];
        }
    }
    for (int e = start + nvec + tid; e < end; e += 256) {
        int row = eidx[e];
        int col = eidx[E + e];
        int b1 = row >> BUCKET_BITS;
        unsigned int o1 = atomicAdd(&cnt2p[b1 >> 1], 1u << ((b1 & 1) * 16));
        int s1 = (int)sstart16[b1] + (int)((o1 >> ((b1 & 1) * 16)) & 0xFFFFu);
        staged[s1] = ((unsigned int)(row & (BUCKET_SIZE - 1)) << 17) | (unsigned int)col;
        int b2 = col >> BUCKET_BITS;
        unsigned int o2 = atomicAdd(&cnt2p[b2 >> 1], 1u << ((b2 & 1) * 16));
        int s2 = (int)sstart16[b2] + (int)((o2 >> ((b2 & 1) * 16)) & 0xFFFFu);
        staged[s2] = ((unsigned int)(col & (BUCKET_SIZE - 1)) << 17) | (unsigned int)row;
    }
    __syncthreads();

    // phase 4: burst-flush per-bucket runs (8 buckets x 8 lanes per wave-iter)
    {
        const int wv = tid >> 6, ln = tid & 63;
        const int grp = ln >> 3;
        const int sub = ln & 7;
        for (int b = wv * 8 + grp; b < NB; b += 32) {
            int cnt_b = hget(histp, b);
            if (cnt_b == 0) continue;
            int src = (int)sstart16[b];
            int dst = (int)base16[b];
            int kmax = min(cnt_b, CAP - dst);   // graceful overflow guard
            if (kmax <= 0) continue;
            unsigned int* dstp = region + (size_t)b * CAP + dst;
            const unsigned int* srcp = staged + src;
            for (int j = sub; j < kmax; j += 8)
                dstp[j] = srcp[j];
        }
    }
}

// ---------------------------------------------------------------------------
// Pass 2: HALF-bucket blocks for full-chip residency. 2*NB = 1564 blocks x
// 256 threads; LDS ~19 KB -> 8 blocks/CU capacity, so all blocks co-resident
// (zero tail). Each block scans its bucket's full payload list, filters the
// half it owns (64 nodes), sorts it, then 4 lanes/node accumulate in regs.
// ---------------------------------------------------------------------------
#define LSQ_ACC(qv)                                                            \
    {                                                                          \
        float dx = (qv).x - me.x;                                              \
        float dy = (qv).y - me.y;                                              \
        float dz = (qv).z - me.z;                                              \
        float dphi = (qv).w - me.w;                                            \
        float nn = sqrtf(dx * dx + dy * dy + dz * dz) + LSQ_EPS;               \
        float w = 1.0f / (nn * nn);                                            \
        float wd = w * dphi;                                                   \
        a00 += w * dx * dx; a01 += w * dx * dy; a02 += w * dx * dz;            \
        a11 += w * dy * dy; a12 += w * dy * dz; a22 += w * dz * dz;            \
        bb0 += wd * dx;     bb1 += wd * dy;     bb2 += wd * dz;                \
    }

__global__ __launch_bounds__(256, 8) void lsq_bucket_reduce_half(
    const float4* __restrict__ pp4,
    const unsigned int* __restrict__ region, const int* __restrict__ g_cursor,
    float* __restrict__ out, int N)
{
    __shared__ unsigned int sorted32[CAP_HALF];  // 18.4 KB
    __shared__ int cnt[64];
    __shared__ int cnt2[64];
    __shared__ int startx[64];

    const int bb = blockIdx.x;
    const int b = bb >> 1;          // bucket
    const int h = bb & 1;           // which half (nodes h*64 .. h*64+63 local)
    const int tid = threadIdx.x;
    const int node_base = (b << BUCKET_BITS) + (h << 6);

    if (tid < 64) { cnt[tid] = 0; cnt2[tid] = 0; }
    __syncthreads();

    int count = g_cursor[b];
    if (count > CAP) count = CAP;
    const unsigned int* reg = region + (size_t)b * CAP;

    // A: filtered histogram over the full bucket list (L2/L3-hot)
    for (int i = tid; i < count; i += 256) {
        unsigned int p = reg[i];
        int rl = (int)(p >> 17);
        if ((rl >> 6) == h) atomicAdd(&cnt[rl & 63], 1);
    }
    __syncthreads();

    // B: 64-wide exclusive scan (wave 0)
    if (tid < 64) {
        int c = cnt[tid];
        int x = c;
#pragma unroll
        for (int d = 1; d < 64; d <<= 1) {
            int y = __shfl_up(x, d, 64);
            if (tid >= d) x += y;
        }
        startx[tid] = x - c;
    }
    __syncthreads();

    // C: filtered counting-sort (other_node stored directly)
    for (int i = tid; i < count; i += 256) {
        unsigned int p = reg[i];
        int rl = (int)(p >> 17);
        if ((rl >> 6) == h) {
            int off = atomicAdd(&cnt2[rl & 63], 1);
            int idx = startx[rl & 63] + off;
            if (idx < CAP_HALF) sorted32[idx] = p & 0x1FFFFu;
        }
    }
    __syncthreads();

    // D: register accumulation, 4 consecutive lanes per node (64 nodes)
    const int n = tid >> 2;          // 0..63
    const int qid = tid & 3;
    int node = node_base + n;
    float4 me = pp4[node < N ? node : 0];
    const int s = startx[n];
    const int cN = cnt[n];
    int lo = s + (cN * qid) / 4;
    const int hi = s + (cN * (qid + 1)) / 4;

    float a00 = 0, a01 = 0, a02 = 0, a11 = 0, a12 = 0, a22 = 0;
    float bb0 = 0, bb1 = 0, bb2 = 0;

    int i = lo;
    for (; i + 3 < hi; i += 4) {
        int c0 = (int)sorted32[i];
        int c1 = (int)sorted32[i + 1];
        int c2 = (int)sorted32[i + 2];
        int c3 = (int)sorted32[i + 3];
        float4 q0 = pp4[c0];
        float4 q1 = pp4[c1];
        float4 q2 = pp4[c2];
        float4 q3 = pp4[c3];
        LSQ_ACC(q0); LSQ_ACC(q1); LSQ_ACC(q2); LSQ_ACC(q3);
    }
    for (; i < hi; ++i) {
        int c0 = (int)sorted32[i];
        float4 q0 = pp4[c0];
        LSQ_ACC(q0);
    }

    // E: shuffle-combine the 4 partials (lanes n*4 .. n*4+3 are in one wave)
    a00 += __shfl_down(a00, 1); a01 += __shfl_down(a01, 1);
    a02 += __shfl_down(a02, 1); a11 += __shfl_down(a11, 1);
    a12 += __shfl_down(a12, 1); a22 += __shfl_down(a22, 1);
    bb0 += __shfl_down(bb0, 1); bb1 += __shfl_down(bb1, 1);
    bb2 += __shfl_down(bb2, 1);
    a00 += __shfl_down(a00, 2); a01 += __shfl_down(a01, 2);
    a02 += __shfl_down(a02, 2); a11 += __shfl_down(a11, 2);
    a12 += __shfl_down(a12, 2); a22 += __shfl_down(a22, 2);
    bb0 += __shfl_down(bb0, 2); bb1 += __shfl_down(bb1, 2);
    bb2 += __shfl_down(bb2, 2);

    if (qid == 0 && node < N) {
        double a00d = (double)a00 + 1e-8;
        double a01d = (double)a01;
        double a02d = (double)a02;
        double a11d = (double)a11 + 1e-8;
        double a12d = (double)a12;
        double a22d = (double)a22 + 1e-8;
        double b0 = (double)bb0;
        double b1 = (double)bb1;
        double b2 = (double)bb2;

        double c00 = a11d * a22d - a12d * a12d;
        double c01 = a02d * a12d - a01d * a22d;
        double c02 = a01d * a12d - a02d * a11d;
        double c11 = a00d * a22d - a02d * a02d;
        double c12 = a01d * a02d - a00d * a12d;
        double c22 = a00d * a11d - a01d * a01d;

        double det = a00d * c00 + a01d * c01 + a02d * c02;
        double inv = 1.0 / det;

        out[node * 3 + 0] = (float)((c00 * b0 + c01 * b1 + c02 * b2) * inv);
        out[node * 3 + 1] = (float)((c01 * b0 + c11 * b1 + c12 * b2) * inv);
        out[node * 3 + 2] = (float)((c02 * b0 + c12 * b1 + c22 * b2) * inv);
    }
}

// ---------------------------------------------------------------------------
// Fallback path (round-1): global float atomics; no structural assumptions.
// ---------------------------------------------------------------------------
__global__ void lsq_edge_scatter(const float* __restrict__ pos,
                                 const float* __restrict__ phi,
                                 const int* __restrict__ eidx,
                                 float* __restrict__ acc,
                                 int E) {
    int e = blockIdx.x * blockDim.x + threadIdx.x;
    if (e >= E) return;
    int r = eidx[e];
    int c = eidx[E + e];
    float dx = pos[3 * c + 0] - pos[3 * r + 0];
    float dy = pos[3 * c + 1] - pos[3 * r + 1];
    float dz = pos[3 * c + 2] - pos[3 * r + 2];
    float dphi = phi[c] - phi[r];
    float n = sqrtf(dx * dx + dy * dy + dz * dz) + LSQ_EPS;
    float w = 1.0f / (n * n);
    float wd = w * dphi;
    float* a = acc + (size_t)r * 9;
    unsafeAtomicAdd(a + 0, w * dx * dx);
    unsafeAtomicAdd(a + 1, w * dx * dy);
    unsafeAtomicAdd(a + 2, w * dx * dz);
    unsafeAtomicAdd(a + 3, w * dy * dy);
    unsafeAtomicAdd(a + 4, w * dy * dz);
    unsafeAtomicAdd(a + 5, w * dz * dz);
    unsafeAtomicAdd(a + 6, wd * dx);
    unsafeAtomicAdd(a + 7, wd * dy);
    unsafeAtomicAdd(a + 8, wd * dz);
}

__global__ void lsq_solve3(const float* __restrict__ acc,
                           float* __restrict__ out,
                           int N) {
    int i = blockIdx.x * blockDim.x + threadIdx.x;
    if (i >= N) return;
    const float* a = acc + (size_t)i * 9;
    double a00 = (double)a[0] + 1e-8;
    double a01 = (double)a[1];
    double a02 = (double)a[2];
    double a11 = (double)a[3] + 1e-8;
    double a12 = (double)a[4];
    double a22 = (double)a[5] + 1e-8;
    double b0 = (double)a[6];
    double b1 = (double)a[7];
    double b2 = (double)a[8];
    double c00 = a11 * a22 - a12 * a12;
    double c01 = a02 * a12 - a01 * a22;
    double c02 = a01 * a12 - a02 * a11;
    double c11 = a00 * a22 - a02 * a02;
    double c12 = a01 * a02 - a00 * a12;
    double c22 = a00 * a11 - a01 * a01;
    double det = a00 * c00 + a01 * c01 + a02 * c02;
    double inv = 1.0 / det;
    out[3 * i + 0] = (float)((c00 * b0 + c01 * b1 + c02 * b2) * inv);
    out[3 * i + 1] = (float)((c01 * b0 + c11 * b1 + c12 * b2) * inv);
    out[3 * i + 2] = (float)((c02 * b0 + c12 * b1 + c22 * b2) * inv);
}

extern "C" void kernel_launch(void* const* d_in, const int* in_sizes, int n_in,
                              void* d_out, int out_size, void* d_ws, size_t ws_size,
                              hipStream_t stream) {
    const float* pos = (const float*)d_in[0];
    const float* phi = (const float*)d_in[1];
    const int* eidx = (const int*)d_in[2];
    float* out = (float*)d_out;

    int N = in_sizes[0] / 3;      // pos is (N,3)
    int E = in_sizes[2] / 2;      // edge_index is (2,E)
    int NB = (N + BUCKET_SIZE - 1) >> BUCKET_BITS;

    size_t region_bytes = (size_t)NB * CAP * sizeof(unsigned int);   // ~28.0 MB
    size_t pp4_bytes = (size_t)N * sizeof(float4);                   // ~1.6 MB
    size_t need = region_bytes + pp4_bytes + (size_t)NB * sizeof(int);

    int chunk = ((E / 2) + SCAT_BLOCKS - 1) / SCAT_BLOCKS;
    chunk = (chunk + 3) & ~3;
    bool stage_ok = (2 * chunk) <= STAGE_CAP;

    if (NB <= NB_MAX && ws_size >= need && (E & 3) == 0 && stage_ok) {
        unsigned int* region = (unsigned int*)d_ws;
        float4* pp4 = (float4*)((char*)d_ws + region_bytes);
        int* g_cursor = (int*)((char*)d_ws + region_bytes + pp4_bytes);

        hipMemsetAsync(g_cursor, 0, (size_t)NB * sizeof(int), stream);
        lsq_scatter_sorted<<<SCAT_BLOCKS, 256, 0, stream>>>(
            pos, phi, eidx, E, N, NB, pp4, region, g_cursor);
        lsq_bucket_reduce_half<<<2 * NB, 256, 0, stream>>>(pp4, region, g_cursor, out, N);
    } else {
        float* acc = (float*)d_ws;
        hipMemsetAsync(acc, 0, (size_t)N * 9 * sizeof(float), stream);
        int threads = 256;
        lsq_edge_scatter<<<(E + threads - 1) / threads, threads, 0, stream>>>(pos, phi, eidx, acc, E);
        lsq_solve3<<<(N + threads - 1) / threads, threads, 0, stream>>>(acc, out, N);
    }
}

// Round 12
// 172.390 us; speedup vs baseline: 1.0890x; 1.0890x over previous
//
#include <hip/hip_runtime.h>
#include <hip/hip_bf16.h>
#include <math.h>

#define LSQ_EPS 1e-8f
#define BUCKET_BITS 7
#define BUCKET_SIZE 128            // nodes per bucket
#define NB_MAX 800                 // max buckets supported by static LDS
#define CAP 8960                   // per-bucket payload capacity (mean ~8184, sigma ~90)
#define SCAT_BLOCKS 1024           // R8-proven optimum: 5 blocks/CU, WRITE ~50 MB
#define STAGE_CAP 6272             // >= 2 * chunk (chunk = ceil(E2/1024) -> 3128)
#define KMAX 18                    // ceil(CAP / 512) payloads per reduce thread

// ---------------------------------------------------------------------------
// Pass 1 (fused pack + sorted scatter) — byte-exact R8 configuration, the
// empirically write-optimal point (512blk: 37MB/75us; 1024blk: 50MB/56us;
// 1536blk: 88MB/76us; reg-cache variant at 1024: 75MB/60us — R10).
// eidx re-read in phase 3 is L3-hot and effectively free; keep it.
// payload u32 = (node_local << 17) | other_node
// ---------------------------------------------------------------------------
__device__ __forceinline__ void hinc(unsigned int* hp, int b) {
    atomicAdd(&hp[b >> 1], 1u << ((b & 1) * 16));
}
__device__ __forceinline__ int hget(const unsigned int* hp, int b) {
    return (int)((hp[b >> 1] >> ((b & 1) * 16)) & 0xFFFFu);
}

__global__ __launch_bounds__(256, 5) void lsq_scatter_sorted(
    const float* __restrict__ pos, const float* __restrict__ phi,
    const int* __restrict__ eidx, int E, int N, int NB,
    float4* __restrict__ pp4,
    unsigned int* __restrict__ region, int* __restrict__ g_cursor)
{
    __shared__ unsigned int staged[STAGE_CAP];     // 25.1 KB
    __shared__ unsigned int histp[NB_MAX / 2];     // 1.6 KB (2x16-bit packed)
    __shared__ unsigned int cnt2p[NB_MAX / 2];     // 1.6 KB (2x16-bit packed)
    __shared__ unsigned short base16[NB_MAX];      // 1.6 KB
    __shared__ unsigned short sstart16[NB_MAX];    // 1.6 KB

    const int tid = threadIdx.x;
    const int E2 = E >> 1;

    // fused pack: pp4[i] = (pos, phi)
    for (int i = blockIdx.x * 256 + tid; i < N; i += SCAT_BLOCKS * 256)
        pp4[i] = make_float4(pos[3 * i + 0], pos[3 * i + 1], pos[3 * i + 2], phi[i]);

    int chunk = (E2 + SCAT_BLOCKS - 1) / SCAT_BLOCKS;
    chunk = (chunk + 3) & ~3;
    const int start = blockIdx.x * chunk;
    const int end = min(start + chunk, E2);
    if (start >= E2) return;

    for (int t = tid; t < NB_MAX / 2; t += 256) { histp[t] = 0; cnt2p[t] = 0; }
    __syncthreads();

    // phase 1: histogram BOTH endpoints
    const int nvec = (end - start) & ~3;
    for (int e = start + (tid << 2); e < start + nvec; e += 1024) {
        int4 r = *(const int4*)(eidx + e);
        int4 c = *(const int4*)(eidx + E + e);
        hinc(histp, r.x >> BUCKET_BITS);
        hinc(histp, r.y >> BUCKET_BITS);
        hinc(histp, r.z >> BUCKET_BITS);
        hinc(histp, r.w >> BUCKET_BITS);
        hinc(histp, c.x >> BUCKET_BITS);
        hinc(histp, c.y >> BUCKET_BITS);
        hinc(histp, c.z >> BUCKET_BITS);
        hinc(histp, c.w >> BUCKET_BITS);
    }
    for (int e = start + nvec + tid; e < end; e += 256) {
        hinc(histp, eidx[e] >> BUCKET_BITS);
        hinc(histp, eidx[E + e] >> BUCKET_BITS);
    }
    __syncthreads();

    // phase 2a: global reservation (one int atomic per non-empty bucket)
    for (int b = tid; b < NB; b += 256) {
        int c = hget(histp, b);
        int bs = (c > 0) ? atomicAdd(&g_cursor[b], c) : 0;
        base16[b] = (unsigned short)min(bs, 65535);
    }
    // phase 2b: block-local exclusive scan of hist -> sstart16 (wave 0)
    if (tid < 64) {
        int carry = 0;
        for (int bi = 0; bi < NB; bi += 64) {
            int b = bi + tid;
            int c = (b < NB) ? hget(histp, b) : 0;
            int x = c;
#pragma unroll
            for (int d = 1; d < 64; d <<= 1) {
                int y = __shfl_up(x, d, 64);
                if (tid >= d) x += y;
            }
            if (b < NB) sstart16[b] = (unsigned short)(carry + x - c);
            carry += __shfl(x, 63, 64);
        }
    }
    __syncthreads();

    // phase 3: counting-sort payloads into LDS staging (eidx re-read: L3-hot)
    for (int e = start + (tid << 2); e < start + nvec; e += 1024) {
        int4 r = *(const int4*)(eidx + e);
        int4 c = *(const int4*)(eidx + E + e);
        int rr[4] = {r.x, r.y, r.z, r.w};
        int cc[4] = {c.x, c.y, c.z, c.w};
#pragma unroll
        for (int k = 0; k < 4; ++k) {
            int b1 = rr[k] >> BUCKET_BITS;
            unsigned int o1 = atomicAdd(&cnt2p[b1 >> 1], 1u << ((b1 & 1) * 16));
            int s1 = (int)sstart16[b1] + (int)((o1 >> ((b1 & 1) * 16)) & 0xFFFFu);
            staged[s1] = ((unsigned int)(rr[k] & (BUCKET_SIZE - 1)) << 17) | (unsigned int)cc[k];
            int b2 = cc[k] >> BUCKET_BITS;
            unsigned int o2 = atomicAdd(&cnt2p[b2 >> 1], 1u << ((b2 & 1) * 16));
            int s2 = (int)sstart16[b2] + (int)((o2 >> ((b2 & 1) * 16)) & 0xFFFFu);
            staged[s2] = ((unsigned int)(cc[k] & (BUCKET_SIZE - 1)) << 17) | (unsigned int)rr[k];
        }
    }
    for (int e = start + nvec + tid; e < end; e += 256) {
        int row = eidx[e];
        int col = eidx[E + e];
        int b1 = row >> BUCKET_BITS;
        unsigned int o1 = atomicAdd(&cnt2p[b1 >> 1], 1u << ((b1 & 1) * 16));
        int s1 = (int)sstart16[b1] + (int)((o1 >> ((b1 & 1) * 16)) & 0xFFFFu);
        staged[s1] = ((unsigned int)(row & (BUCKET_SIZE - 1)) << 17) | (unsigned int)col;
        int b2 = col >> BUCKET_BITS;
        unsigned int o2 = atomicAdd(&cnt2p[b2 >> 1], 1u << ((b2 & 1) * 16));
        int s2 = (int)sstart16[b2] + (int)((o2 >> ((b2 & 1) * 16)) & 0xFFFFu);
        staged[s2] = ((unsigned int)(col & (BUCKET_SIZE - 1)) << 17) | (unsigned int)row;
    }
    __syncthreads();

    // phase 4: burst-flush per-bucket runs (8 buckets x 8 lanes per wave-iter)
    {
        const int wv = tid >> 6, ln = tid & 63;
        const int grp = ln >> 3;
        const int sub = ln & 7;
        for (int b = wv * 8 + grp; b < NB; b += 32) {
            int cnt_b = hget(histp, b);
            if (cnt_b == 0) continue;
            int src = (int)sstart16[b];
            int dst = (int)base16[b];
            int kmax = min(cnt_b, CAP - dst);   // graceful overflow guard
            if (kmax <= 0) continue;
            unsigned int* dstp = region + (size_t)b * CAP + dst;
            const unsigned int* srcp = staged + src;
            for (int j = sub; j < kmax; j += 8)
                dstp[j] = srcp[j];
        }
    }
}

// ---------------------------------------------------------------------------
// Pass 2: one workgroup per bucket (128 nodes, 512 threads) — R8 structure
// with the C-phase cursor atomic ELIMINATED: phase A's histogram atomicAdd
// return value IS this payload's within-node rank; pack it into the cached
// payload's spare high byte (payload bits 0..23, rank bits 24..31 — degree
// is Poisson(64), sigma=8, so rank < 256 at ~24 sigma). Phase C becomes a
// plain ds_write. LDS-queue ops per payload: 4 -> 3.
// ---------------------------------------------------------------------------
#define LSQ_ACC(qv)                                                            \
    {                                                                          \
        float dx = (qv).x - me.x;                                              \
        float dy = (qv).y - me.y;                                              \
        float dz = (qv).z - me.z;                                              \
        float dphi = (qv).w - me.w;                                            \
        float nn = sqrtf(dx * dx + dy * dy + dz * dz) + LSQ_EPS;               \
        float w = 1.0f / (nn * nn);                                            \
        float wd = w * dphi;                                                   \
        a00 += w * dx * dx; a01 += w * dx * dy; a02 += w * dx * dz;            \
        a11 += w * dy * dy; a12 += w * dy * dz; a22 += w * dz * dz;            \
        bb0 += wd * dx;     bb1 += wd * dy;     bb2 += wd * dz;                \
    }

__global__ __launch_bounds__(512, 8) void lsq_bucket_reduce(
    const float4* __restrict__ pp4,
    const unsigned int* __restrict__ region, const int* __restrict__ g_cursor,
    float* __restrict__ out, int N)
{
    __shared__ unsigned int sorted32[CAP];       // 35.8 KB
    __shared__ int cnt[BUCKET_SIZE];
    __shared__ int startx[BUCKET_SIZE];

    const int b = blockIdx.x;
    const int tid = threadIdx.x;
    const int node_base = b << BUCKET_BITS;

    if (tid < BUCKET_SIZE) cnt[tid] = 0;
    __syncthreads();

    int count = g_cursor[b];
    if (count > CAP) count = CAP;
    const unsigned int* reg = region + (size_t)b * CAP;

    // A: histogram + register-cache payloads with rank packed in bits 24..31
    unsigned int pc[KMAX];
#pragma unroll
    for (int k = 0; k < KMAX; ++k) {
        int i = tid + k * 512;
        if (i < count) {
            unsigned int p = reg[i];
            unsigned int off = (unsigned int)atomicAdd(&cnt[p >> 17], 1);
            pc[k] = p | (off << 24);
        }
    }
    __syncthreads();

    // B: exclusive scan over 128 counts (wave 0, two chained 64-wide scans)
    if (tid < 64) {
        int c0 = cnt[tid];
        int c1 = cnt[tid + 64];
        int x0 = c0, x1 = c1;
#pragma unroll
        for (int d = 1; d < 64; d <<= 1) {
            int y0 = __shfl_up(x0, d, 64);
            int y1 = __shfl_up(x1, d, 64);
            if (tid >= d) { x0 += y0; x1 += y1; }
        }
        int tot0 = __shfl(x0, 63, 64);
        startx[tid] = x0 - c0;
        startx[tid + 64] = tot0 + x1 - c1;
    }
    __syncthreads();

    // C: place cached payloads by precomputed rank (plain ds_write, no atomic)
#pragma unroll
    for (int k = 0; k < KMAX; ++k) {
        int i = tid + k * 512;
        if (i < count) {
            unsigned int p = pc[k];
            int rl = (int)((p >> 17) & 0x7Fu);
            int off = (int)(p >> 24);
            sorted32[startx[rl] + off] = p & 0x1FFFFu;
        }
    }
    __syncthreads();

    // D: register accumulation, 4 consecutive lanes per node
    const int n = tid >> 2;          // 0..127
    const int qid = tid & 3;
    int node = node_base + n;
    float4 me = pp4[node < N ? node : 0];
    const int s = startx[n];
    const int cN = cnt[n];
    int lo = s + (cN * qid) / 4;
    const int hi = s + (cN * (qid + 1)) / 4;

    float a00 = 0, a01 = 0, a02 = 0, a11 = 0, a12 = 0, a22 = 0;
    float bb0 = 0, bb1 = 0, bb2 = 0;

    int i = lo;
    for (; i + 3 < hi; i += 4) {
        int c0 = (int)sorted32[i];
        int c1 = (int)sorted32[i + 1];
        int c2 = (int)sorted32[i + 2];
        int c3 = (int)sorted32[i + 3];
        float4 q0 = pp4[c0];
        float4 q1 = pp4[c1];
        float4 q2 = pp4[c2];
        float4 q3 = pp4[c3];
        LSQ_ACC(q0); LSQ_ACC(q1); LSQ_ACC(q2); LSQ_ACC(q3);
    }
    for (; i < hi; ++i) {
        int c0 = (int)sorted32[i];
        float4 q0 = pp4[c0];
        LSQ_ACC(q0);
    }

    // E: shuffle-combine the 4 partials (lanes n*4 .. n*4+3 are in one wave)
    a00 += __shfl_down(a00, 1); a01 += __shfl_down(a01, 1);
    a02 += __shfl_down(a02, 1); a11 += __shfl_down(a11, 1);
    a12 += __shfl_down(a12, 1); a22 += __shfl_down(a22, 1);
    bb0 += __shfl_down(bb0, 1); bb1 += __shfl_down(bb1, 1);
    bb2 += __shfl_down(bb2, 1);
    a00 += __shfl_down(a00, 2); a01 += __shfl_down(a01, 2);
    a02 += __shfl_down(a02, 2); a11 += __shfl_down(a11, 2);
    a12 += __shfl_down(a12, 2); a22 += __shfl_down(a22, 2);
    bb0 += __shfl_down(bb0, 2); bb1 += __shfl_down(bb1, 2);
    bb2 += __shfl_down(bb2, 2);

    if (qid == 0 && node < N) {
        double a00d = (double)a00 + 1e-8;
        double a01d = (double)a01;
        double a02d = (double)a02;
        double a11d = (double)a11 + 1e-8;
        double a12d = (double)a12;
        double a22d = (double)a22 + 1e-8;
        double b0 = (double)bb0;
        double b1 = (double)bb1;
        double b2 = (double)bb2;

        double c00 = a11d * a22d - a12d * a12d;
        double c01 = a02d * a12d - a01d * a22d;
        double c02 = a01d * a12d - a02d * a11d;
        double c11 = a00d * a22d - a02d * a02d;
        double c12 = a01d * a02d - a00d * a12d;
        double c22 = a00d * a11d - a01d * a01d;

        double det = a00d * c00 + a01d * c01 + a02d * c02;
        double inv = 1.0 / det;

        out[node * 3 + 0] = (float)((c00 * b0 + c01 * b1 + c02 * b2) * inv);
        out[node * 3 + 1] = (float)((c01 * b0 + c11 * b1 + c12 * b2) * inv);
        out[node * 3 + 2] = (float)((c02 * b0 + c12 * b1 + c22 * b2) * inv);
    }
}

// ---------------------------------------------------------------------------
// Fallback path (round-1): global float atomics; no structural assumptions.
// ---------------------------------------------------------------------------
__global__ void lsq_edge_scatter(const float* __restrict__ pos,
                                 const float* __restrict__ phi,
                                 const int* __restrict__ eidx,
                                 float* __restrict__ acc,
                                 int E) {
    int e = blockIdx.x * blockDim.x + threadIdx.x;
    if (e >= E) return;
    int r = eidx[e];
    int c = eidx[E + e];
    float dx = pos[3 * c + 0] - pos[3 * r + 0];
    float dy = pos[3 * c + 1] - pos[3 * r + 1];
    float dz = pos[3 * c + 2] - pos[3 * r + 2];
    float dphi = phi[c] - phi[r];
    float n = sqrtf(dx * dx + dy * dy + dz * dz) + LSQ_EPS;
    float w = 1.0f / (n * n);
    float wd = w * dphi;
    float* a = acc + (size_t)r * 9;
    unsafeAtomicAdd(a + 0, w * dx * dx);
    unsafeAtomicAdd(a + 1, w * dx * dy);
    unsafeAtomicAdd(a + 2, w * dx * dz);
    unsafeAtomicAdd(a + 3, w * dy * dy);
    unsafeAtomicAdd(a + 4, w * dy * dz);
    unsafeAtomicAdd(a + 5, w * dz * dz);
    unsafeAtomicAdd(a + 6, wd * dx);
    unsafeAtomicAdd(a + 7, wd * dy);
    unsafeAtomicAdd(a + 8, wd * dz);
}

__global__ void lsq_solve3(const float* __restrict__ acc,
                           float* __restrict__ out,
                           int N) {
    int i = blockIdx.x * blockDim.x + threadIdx.x;
    if (i >= N) return;
    const float* a = acc + (size_t)i * 9;
    double a00 = (double)a[0] + 1e-8;
    double a01 = (double)a[1];
    double a02 = (double)a[2];
    double a11 = (double)a[3] + 1e-8;
    double a12 = (double)a[4];
    double a22 = (double)a[5] + 1e-8;
    double b0 = (double)a[6];
    double b1 = (double)a[7];
    double b2 = (double)a[8];
    double c00 = a11 * a22 - a12 * a12;
    double c01 = a02 * a12 - a01 * a22;
    double c02 = a01 * a12 - a02 * a11;
    double c11 = a00 * a22 - a02 * a02;
    double c12 = a01 * a02 - a00 * a12;
    double c22 = a00 * a11 - a01 * a01;
    double det = a00 * c00 + a01 * c01 + a02 * c02;
    double inv = 1.0 / det;
    out[3 * i + 0] = (float)((c00 * b0 + c01 * b1 + c02 * b2) * inv);
    out[3 * i + 1] = (float)((c01 * b0 + c11 * b1 + c12 * b2) * inv);
    out[3 * i + 2] = (float)((c02 * b0 + c12 * b1 + c22 * b2) * inv);
}

extern "C" void kernel_launch(void* const* d_in, const int* in_sizes, int n_in,
                              void* d_out, int out_size, void* d_ws, size_t ws_size,
                              hipStream_t stream) {
    const float* pos = (const float*)d_in[0];
    const float* phi = (const float*)d_in[1];
    const int* eidx = (const int*)d_in[2];
    float* out = (float*)d_out;

    int N = in_sizes[0] / 3;      // pos is (N,3)
    int E = in_sizes[2] / 2;      // edge_index is (2,E)
    int NB = (N + BUCKET_SIZE - 1) >> BUCKET_BITS;

    size_t region_bytes = (size_t)NB * CAP * sizeof(unsigned int);   // ~28.0 MB
    size_t pp4_bytes = (size_t)N * sizeof(float4);                   // ~1.6 MB
    size_t need = region_bytes + pp4_bytes + (size_t)NB * sizeof(int);

    int chunk = ((E / 2) + SCAT_BLOCKS - 1) / SCAT_BLOCKS;
    chunk = (chunk + 3) & ~3;
    bool stage_ok = (2 * chunk) <= STAGE_CAP;

    if (NB <= NB_MAX && ws_size >= need && (E & 3) == 0 && stage_ok) {
        unsigned int* region = (unsigned int*)d_ws;
        float4* pp4 = (float4*)((char*)d_ws + region_bytes);
        int* g_cursor = (int*)((char*)d_ws + region_bytes + pp4_bytes);

        hipMemsetAsync(g_cursor, 0, (size_t)NB * sizeof(int), stream);
        lsq_scatter_sorted<<<SCAT_BLOCKS, 256, 0, stream>>>(
            pos, phi, eidx, E, N, NB, pp4, region, g_cursor);
        lsq_bucket_reduce<<<NB, 512, 0, stream>>>(pp4, region, g_cursor, out, N);
    } else {
        float* acc = (float*)d_ws;
        hipMemsetAsync(acc, 0, (size_t)N * 9 * sizeof(float), stream);
        int threads = 256;
        lsq_edge_scatter<<<(E + threads - 1) / threads, threads, 0, stream>>>(pos, phi, eidx, acc, E);
        lsq_solve3<<<(N + threads - 1) / threads, threads, 0, stream>>>(acc, out, N);
    }
}